// Round 5
// baseline (100.316 us; speedup 1.0000x reference)
//
#include <hip/hip_runtime.h>

// QuantizedConv1d on MI355X (gfx950) — round 5
// B=32, CIN=128, L=4096, COUT=256, K=5, replication pad 2.
//   wprep_kernel: W int32 -> Wt bf16 [5][256][128]  (tiny)
//   conv_fused:   x f32 -> quantize+transpose into swizzled LDS, bf16 MFMA,
//                 int32 output. Block = 256co x 256l (1024 thr, 16 waves).
// Round-4 post-mortem: staging WRITE bank conflicts (8.9M cyc) — rows stride
// 4 per lane so XOR with (r&7) hit 2 slots. Fix: XOR with ((r>>2)&7) on both
// sides (write rows r=4*lg+m -> r>>2=lg varies per lane). Also: one block
// covers all 256 co (x fetched+quantized once, not twice).

#define B_    32
#define CIN   128
#define LEN   4096
#define COUT  256
#define KW    5
#define LTROWS 264   // staged rows: gl in [l0-4, l0+259]; rows 2..261 feed taps

typedef float          f32x4 __attribute__((ext_vector_type(4)));
typedef short          s16x8 __attribute__((ext_vector_type(8)));
typedef unsigned short u16;
typedef u16            u16x4 __attribute__((ext_vector_type(4)));

// round-half-even(x/0.05) - 3, clip to [-128,127], as bf16 bit pattern.
// IEEE division to match jnp bit-for-bit; integers |v|<=128 exact in bf16.
__device__ __forceinline__ u16 quant_bf16(float xv) {
    float q = rintf(__fdiv_rn(xv, 0.05f)) - 3.0f;
    q = fminf(fmaxf(q, -128.0f), 127.0f);
    return (u16)(__float_as_uint(q) >> 16);
}

__global__ __launch_bounds__(256) void wprep_kernel(
        const int* __restrict__ w, u16* __restrict__ wt)
{
    int o  = blockIdx.x * 256 + threadIdx.x;   // 40960 total, 4 ci each
    int c4 = o & 31, co = (o >> 5) & 255, k = o >> 13;
    int ci = c4 << 2;
    u16 q[4];
    #pragma unroll
    for (int j = 0; j < 4; ++j) {
        float f = (float)w[co * (CIN * KW) + (ci + j) * KW + k];  // |v|<=127 exact
        q[j] = (u16)(__float_as_uint(f) >> 16);
    }
    u16x4 v4 = { q[0], q[1], q[2], q[3] };
    *(u16x4*)(wt + ((size_t)k * COUT + co) * CIN + ci) = v4;
}

// Swizzled LDS addressing. Row = 256B = 16 chunks of 16B; banks alias every
// 8 chunks. XOR the low-3 chunk bits with (row>>2)&7: staging writes stride
// rows by 4 per lane (r>>2 = lane quad-id -> 8 slots, conflict-free) and
// K-loop reads span 16 rows per lane-group (4 slots -> volume-limited).
__device__ __forceinline__ int lds_byte(int row, int chunk16) {
    int slot = (chunk16 & 8) | ((chunk16 ^ (row >> 2)) & 7);
    return (row << 8) + (slot << 4);
}
__device__ __forceinline__ void stage_write(u16* smem, int row, int ci, u16x4 v) {
    *(u16x4*)((char*)smem + lds_byte(row, ci >> 3) + ((ci & 4) << 1)) = v;
}

// Block: 256 co x 256 l, 1024 threads, 16 waves = 8 co-waves x 2 l-waves.
// Wave = 32co x 128l, acc[2][8]. LDS: X tile [264][128] bf16 swizzled, 67.5KB.
// W frags from global (320KB, L2-resident; prefetched per tap into regs).
__global__ __launch_bounds__(1024) void conv_fused(
        const float* __restrict__ x, const u16* __restrict__ wt,
        const int* __restrict__ bias, const float* __restrict__ wscale,
        int* __restrict__ out)
{
    __shared__ u16 smem[LTROWS * CIN];   // 67,584 B

    int bid   = blockIdx.x;
    int b     = bid >> 4;
    int ltile = bid & 15;
    int l0    = ltile << 8;
    int tid   = threadIdx.x;
    int wid   = tid >> 6, lane = tid & 63;
    int lr    = lane & 15, lh = lane >> 4;
    int cog   = (wid & 7) << 5;          // wave co base: 8 x 32
    int wl    = (wid >> 3) << 7;         // wave local-l base: {0, 128}

    const float* xb = x + (size_t)b * CIN * LEN;

    // ---- stage: quantize + transpose x[b][*][l0-4 .. l0+259] into LDS ----
    // LDS row r <-> global l = l0 - 4 + r (clamped at sequence edges).
    bool interior = (ltile >= 1) && (ltile <= 14);
    if (interior) {
        const float* xs = xb + (l0 - 4);             // 16B-aligned rows
        #pragma unroll
        for (int it = 0; it < 2; ++it) {
            int p  = (it << 10) + tid;               // 4ci x 4l patches
            int lg = p & 63, cg = p >> 6;            // lanes consecutive in l
            int ci = cg << 2, r0 = lg << 2;
            u16 q[4][4];
            #pragma unroll
            for (int j = 0; j < 4; ++j) {
                f32x4 f = *(const f32x4*)(xs + (size_t)(ci + j) * LEN + r0);
                #pragma unroll
                for (int m = 0; m < 4; ++m) q[j][m] = quant_bf16(f[m]);
            }
            #pragma unroll
            for (int m = 0; m < 4; ++m) {
                u16x4 v = { q[0][m], q[1][m], q[2][m], q[3][m] };
                stage_write(smem, r0 + m, ci, v);
            }
        }
        if (tid < 64) {                              // tail rows 256..263
            int cg = tid & 31, ci = cg << 2;
            int r0 = 256 + ((tid >> 5) << 2);
            u16 q[4][4];
            #pragma unroll
            for (int j = 0; j < 4; ++j) {
                f32x4 f = *(const f32x4*)(xs + (size_t)(ci + j) * LEN + r0);
                #pragma unroll
                for (int m = 0; m < 4; ++m) q[j][m] = quant_bf16(f[m]);
            }
            #pragma unroll
            for (int m = 0; m < 4; ++m) {
                u16x4 v = { q[0][m], q[1][m], q[2][m], q[3][m] };
                stage_write(smem, r0 + m, ci, v);
            }
        }
    } else {
        // edge blocks: scalar loads with replication clamp
        #pragma unroll
        for (int it = 0; it < 2; ++it) {
            int p  = (it << 10) + tid;
            int lg = p & 63, cg = p >> 6;
            int ci = cg << 2, r0 = lg << 2;
            u16 q[4][4];
            #pragma unroll
            for (int j = 0; j < 4; ++j)
                #pragma unroll
                for (int m = 0; m < 4; ++m) {
                    int gl = l0 - 4 + r0 + m;
                    gl = min(max(gl, 0), LEN - 1);
                    q[j][m] = quant_bf16(xb[(size_t)(ci + j) * LEN + gl]);
                }
            #pragma unroll
            for (int m = 0; m < 4; ++m) {
                u16x4 v = { q[0][m], q[1][m], q[2][m], q[3][m] };
                stage_write(smem, r0 + m, ci, v);
            }
        }
        if (tid < 64) {
            int cg = tid & 31, ci = cg << 2;
            int r0 = 256 + ((tid >> 5) << 2);
            u16 q[4][4];
            #pragma unroll
            for (int j = 0; j < 4; ++j)
                #pragma unroll
                for (int m = 0; m < 4; ++m) {
                    int gl = l0 - 4 + r0 + m;
                    gl = min(max(gl, 0), LEN - 1);
                    q[j][m] = quant_bf16(xb[(size_t)(ci + j) * LEN + gl]);
                }
            #pragma unroll
            for (int m = 0; m < 4; ++m) {
                u16x4 v = { q[0][m], q[1][m], q[2][m], q[3][m] };
                stage_write(smem, r0 + m, ci, v);
            }
        }
    }
    __syncthreads();

    // ---- K-loop: 5 taps; per tap prefetch 8 W-frags, then 4 ci-quarters ----
    f32x4 acc[2][8] = {};
    #pragma unroll
    for (int k = 0; k < KW; ++k) {
        s16x8 af[4][2];
        #pragma unroll
        for (int s = 0; s < 4; ++s)
            #pragma unroll
            for (int ct = 0; ct < 2; ++ct)
                af[s][ct] = *(const s16x8*)(
                    wt + ((size_t)k * COUT + cog + ct * 16 + lr) * CIN + (s << 5) + (lh << 3));
        #pragma unroll
        for (int s = 0; s < 4; ++s) {
            int chunk = (s << 2) + lh;
            #pragma unroll
            for (int lt = 0; lt < 8; ++lt) {
                int row = wl + (lt << 4) + lr + k + 2;
                s16x8 bf = *(const s16x8*)((const char*)smem + lds_byte(row, chunk));
                acc[0][lt] = __builtin_amdgcn_mfma_f32_16x16x32_bf16(af[s][0], bf, acc[0][lt], 0, 0, 0);
                acc[1][lt] = __builtin_amdgcn_mfma_f32_16x16x32_bf16(af[s][1], bf, acc[1][lt], 0, 0, 0);
            }
        }
    }

    // ---- requant epilogue (exact reference arithmetic), int32 stores ----
    size_t outb = (size_t)b * COUT * LEN;
    #pragma unroll
    for (int ct = 0; ct < 2; ++ct) {
        #pragma unroll
        for (int r = 0; r < 4; ++r) {
            int co = cog + ct * 16 + (lh << 2) + r;
            float scv = __fdiv_rn(__fmul_rn(0.05f, wscale[co]), 0.1f);
            float bs  = (float)bias[co];
            #pragma unroll
            for (int lt = 0; lt < 8; ++lt) {
                int l = l0 + wl + (lt << 4) + lr;
                float a = __fadd_rn(acc[ct][lt][r], bs);
                float o = __fadd_rn(__fmul_rn(a, scv), -128.0f);
                o = rintf(o);
                o = fminf(fmaxf(o, -128.0f), 127.0f);
                out[outb + (size_t)co * LEN + l] = (int)o;
            }
        }
    }
}

extern "C" void kernel_launch(void* const* d_in, const int* in_sizes, int n_in,
                              void* d_out, int out_size, void* d_ws, size_t ws_size,
                              hipStream_t stream)
{
    const float* x    = (const float*)d_in[0];
    const int*   w    = (const int*)d_in[1];
    const int*   bias = (const int*)d_in[2];
    const float* wsc  = (const float*)d_in[3];
    int* out = (int*)d_out;

    u16* wt = (u16*)d_ws;   // 327,680 bytes

    wprep_kernel<<<dim3(160), dim3(256), 0, stream>>>(w, wt);
    conv_fused<<<dim3(B_ * 16), dim3(1024), 0, stream>>>(x, wt, bias, wsc, out);
}

// Round 6
// 98.059 us; speedup vs baseline: 1.0230x; 1.0230x over previous
//
#include <hip/hip_runtime.h>

// QuantizedConv1d on MI355X (gfx950) — round 6
// B=32, CIN=128, L=4096, COUT=256, K=5, replication pad 2.
//   wprep_kernel: W int32 -> Wt bf16 [5][256][128] + requant table (sc, off)
//   conv_fused:   x f32 -> quantize+transpose into swizzled LDS, bf16 MFMA,
//                 int32 output. Block = 256co x 256l (1024 thr, 16 waves).
// Round-5 post-mortem: swizzle (row>>2) fixed writes but broke reads (22.3M
// conflict cycles — lane-groups collapsed onto 4 of 8 bank-slots). Fix:
// XOR with (row&7)^((row>>2)&7) — even spread for BOTH row-stride-4 writes
// and row-stride-1 reads. Also: quant via x*20.0f (threshold 2.56 tolerates
// sub-ulp divergence from x/0.05), and table-ized requant epilogue.

#define B_    32
#define CIN   128
#define LEN   4096
#define COUT  256
#define KW    5
#define LTROWS 264   // staged rows: gl in [l0-4, l0+259]; rows 2..261 feed taps

#define WT_USHORTS ((size_t)KW * COUT * CIN)   // 163,840

typedef float          f32x4 __attribute__((ext_vector_type(4)));
typedef short          s16x8 __attribute__((ext_vector_type(8)));
typedef unsigned short u16;
typedef u16            u16x4 __attribute__((ext_vector_type(4)));

// round-half-even(x*20) - 3, clip to [-128,127], as bf16 bit pattern.
// x*20f vs x/0.05f differ by <=1ulp; flips are ~1e-6/element and each shifts
// an output by <=0.64 — well inside the 2.56 absmax threshold.
__device__ __forceinline__ u16 quant_bf16(float xv) {
    float q = rintf(xv * 20.0f) - 3.0f;
    q = fminf(fmaxf(q, -128.0f), 127.0f);
    return (u16)(__float_as_uint(q) >> 16);
}

__global__ __launch_bounds__(256) void wprep_kernel(
        const int* __restrict__ w, const int* __restrict__ bias,
        const float* __restrict__ wscale,
        u16* __restrict__ wt, float* __restrict__ tbl)
{
    int o  = blockIdx.x * 256 + threadIdx.x;   // 40960 total, 4 ci each
    int c4 = o & 31, co = (o >> 5) & 255, k = o >> 13;
    int ci = c4 << 2;
    u16 q[4];
    #pragma unroll
    for (int j = 0; j < 4; ++j) {
        float f = (float)w[co * (CIN * KW) + (ci + j) * KW + k];  // |v|<=127 exact
        q[j] = (u16)(__float_as_uint(f) >> 16);
    }
    u16x4 v4 = { q[0], q[1], q[2], q[3] };
    *(u16x4*)(wt + ((size_t)k * COUT + co) * CIN + ci) = v4;

    if (blockIdx.x == 0) {                      // requant table: sc, off
        int c = threadIdx.x;                    // 0..255
        float sc = __fdiv_rn(__fmul_rn(0.05f, wscale[c]), 0.1f);
        tbl[c]       = sc;
        tbl[256 + c] = fmaf((float)bias[c], sc, -128.0f);
    }
}

// Swizzled LDS addressing. Row = 256B = 16 chunks of 16B; banks alias every
// 8 chunks. slot = chunk ^ (row&7) ^ ((row>>2)&7):
//  - staging writes (rows 4*lane+m): (4(lane&1)+m)^(lane&7) hits all 8 slots
//  - K-loop reads (16 consecutive rows/lane-group): uniform over 8 slots
__device__ __forceinline__ int lds_byte(int row, int chunk16) {
    int sw   = (row & 7) ^ ((row >> 2) & 7);
    int slot = (chunk16 & 8) | ((chunk16 ^ sw) & 7);
    return (row << 8) + (slot << 4);
}
__device__ __forceinline__ void stage_write(u16* smem, int row, int ci, u16x4 v) {
    *(u16x4*)((char*)smem + lds_byte(row, ci >> 3) + ((ci & 4) << 1)) = v;
}

// Block: 256 co x 256 l, 1024 threads, 16 waves = 8 co-waves x 2 l-waves.
// Wave = 32co x 128l, acc[2][8]. LDS: X tile [264][128] bf16 swizzled, 67.5KB.
// W frags from global (320KB, L2-resident; prefetched per tap into regs).
__global__ __launch_bounds__(1024) void conv_fused(
        const float* __restrict__ x, const u16* __restrict__ wt,
        const float* __restrict__ tbl, int* __restrict__ out)
{
    __shared__ u16 smem[LTROWS * CIN];   // 67,584 B

    int bid   = blockIdx.x;
    int b     = bid >> 4;
    int ltile = bid & 15;
    int l0    = ltile << 8;
    int tid   = threadIdx.x;
    int wid   = tid >> 6, lane = tid & 63;
    int lr    = lane & 15, lh = lane >> 4;
    int cog   = (wid & 7) << 5;          // wave co base: 8 x 32
    int wl    = (wid >> 3) << 7;         // wave local-l base: {0, 128}

    const float* xb = x + (size_t)b * CIN * LEN;

    // ---- stage: quantize + transpose x[b][*][l0-4 .. l0+259] into LDS ----
    // LDS row r <-> global l = l0 - 4 + r (clamped at sequence edges).
    bool interior = (ltile >= 1) && (ltile <= 14);
    if (interior) {
        const float* xs = xb + (l0 - 4);             // 16B-aligned rows
        #pragma unroll
        for (int it = 0; it < 2; ++it) {
            int p  = (it << 10) + tid;               // 4ci x 4l patches
            int lg = p & 63, cg = p >> 6;            // lanes consecutive in l
            int ci = cg << 2, r0 = lg << 2;
            u16 q[4][4];
            #pragma unroll
            for (int j = 0; j < 4; ++j) {
                f32x4 f = *(const f32x4*)(xs + (size_t)(ci + j) * LEN + r0);
                #pragma unroll
                for (int m = 0; m < 4; ++m) q[j][m] = quant_bf16(f[m]);
            }
            #pragma unroll
            for (int m = 0; m < 4; ++m) {
                u16x4 v = { q[0][m], q[1][m], q[2][m], q[3][m] };
                stage_write(smem, r0 + m, ci, v);
            }
        }
        if (tid < 64) {                              // tail rows 256..263
            int cg = tid & 31, ci = cg << 2;
            int r0 = 256 + ((tid >> 5) << 2);
            u16 q[4][4];
            #pragma unroll
            for (int j = 0; j < 4; ++j) {
                f32x4 f = *(const f32x4*)(xs + (size_t)(ci + j) * LEN + r0);
                #pragma unroll
                for (int m = 0; m < 4; ++m) q[j][m] = quant_bf16(f[m]);
            }
            #pragma unroll
            for (int m = 0; m < 4; ++m) {
                u16x4 v = { q[0][m], q[1][m], q[2][m], q[3][m] };
                stage_write(smem, r0 + m, ci, v);
            }
        }
    } else {
        // edge blocks: scalar loads with replication clamp
        #pragma unroll
        for (int it = 0; it < 2; ++it) {
            int p  = (it << 10) + tid;
            int lg = p & 63, cg = p >> 6;
            int ci = cg << 2, r0 = lg << 2;
            u16 q[4][4];
            #pragma unroll
            for (int j = 0; j < 4; ++j)
                #pragma unroll
                for (int m = 0; m < 4; ++m) {
                    int gl = l0 - 4 + r0 + m;
                    gl = min(max(gl, 0), LEN - 1);
                    q[j][m] = quant_bf16(xb[(size_t)(ci + j) * LEN + gl]);
                }
            #pragma unroll
            for (int m = 0; m < 4; ++m) {
                u16x4 v = { q[0][m], q[1][m], q[2][m], q[3][m] };
                stage_write(smem, r0 + m, ci, v);
            }
        }
        if (tid < 64) {
            int cg = tid & 31, ci = cg << 2;
            int r0 = 256 + ((tid >> 5) << 2);
            u16 q[4][4];
            #pragma unroll
            for (int j = 0; j < 4; ++j)
                #pragma unroll
                for (int m = 0; m < 4; ++m) {
                    int gl = l0 - 4 + r0 + m;
                    gl = min(max(gl, 0), LEN - 1);
                    q[j][m] = quant_bf16(xb[(size_t)(ci + j) * LEN + gl]);
                }
            #pragma unroll
            for (int m = 0; m < 4; ++m) {
                u16x4 v = { q[0][m], q[1][m], q[2][m], q[3][m] };
                stage_write(smem, r0 + m, ci, v);
            }
        }
    }
    __syncthreads();

    // ---- K-loop: 5 taps; per tap prefetch 8 W-frags, then 4 ci-quarters ----
    f32x4 acc[2][8] = {};
    #pragma unroll
    for (int k = 0; k < KW; ++k) {
        s16x8 af[4][2];
        #pragma unroll
        for (int s = 0; s < 4; ++s)
            #pragma unroll
            for (int ct = 0; ct < 2; ++ct)
                af[s][ct] = *(const s16x8*)(
                    wt + ((size_t)k * COUT + cog + ct * 16 + lr) * CIN + (s << 5) + (lh << 3));
        #pragma unroll
        for (int s = 0; s < 4; ++s) {
            int chunk = (s << 2) + lh;
            #pragma unroll
            for (int lt = 0; lt < 8; ++lt) {
                int row = wl + (lt << 4) + lr + k + 2;
                s16x8 bf = *(const s16x8*)((const char*)smem + lds_byte(row, chunk));
                acc[0][lt] = __builtin_amdgcn_mfma_f32_16x16x32_bf16(af[s][0], bf, acc[0][lt], 0, 0, 0);
                acc[1][lt] = __builtin_amdgcn_mfma_f32_16x16x32_bf16(af[s][1], bf, acc[1][lt], 0, 0, 0);
            }
        }
    }

    // ---- requant epilogue via table: rint(fma(acc, sc, off)), int32 stores ----
    size_t outb = (size_t)b * COUT * LEN;
    #pragma unroll
    for (int ct = 0; ct < 2; ++ct) {
        #pragma unroll
        for (int r = 0; r < 4; ++r) {
            int co = cog + ct * 16 + (lh << 2) + r;
            float scv = tbl[co];
            float off = tbl[256 + co];
            #pragma unroll
            for (int lt = 0; lt < 8; ++lt) {
                int l = l0 + wl + (lt << 4) + lr;
                float o = rintf(fmaf(acc[ct][lt][r], scv, off));
                o = fminf(fmaxf(o, -128.0f), 127.0f);
                out[outb + (size_t)co * LEN + l] = (int)o;
            }
        }
    }
}

extern "C" void kernel_launch(void* const* d_in, const int* in_sizes, int n_in,
                              void* d_out, int out_size, void* d_ws, size_t ws_size,
                              hipStream_t stream)
{
    const float* x    = (const float*)d_in[0];
    const int*   w    = (const int*)d_in[1];
    const int*   bias = (const int*)d_in[2];
    const float* wsc  = (const float*)d_in[3];
    int* out = (int*)d_out;

    u16*   wt  = (u16*)d_ws;                    // 327,680 B
    float* tbl = (float*)((char*)d_ws + WT_USHORTS * sizeof(u16));  // +2 KB

    wprep_kernel<<<dim3(160), dim3(256), 0, stream>>>(w, bias, wsc, wt, tbl);
    conv_fused<<<dim3(B_ * 16), dim3(1024), 0, stream>>>(x, wt, tbl, out);
}

// Round 8
// 77.817 us; speedup vs baseline: 1.2891x; 1.2601x over previous
//
#include <hip/hip_runtime.h>

// QuantizedConv1d on MI355X (gfx950) — round 8 (round-7 fix: stray f32x4 line)
// B=32, CIN=128, L=4096, COUT=256, K=5, replication pad 2.
//   wprep_kernel: W int32 -> fragment-linear bf16 wtf[320 frags][64 lanes][8]
//                 (one wave A-frag load = one coalesced 1KB dwordx4) + requant tbl
//   conv_fused:   512 thr, 8 waves = 4co x 2l, wave = 64co x 64l (acc 4x4).
//                 Staging: lane-per-row chunk build (8 coalesced dword loads),
//                 b128 LDS writes, swizzle chunk^=(row&7) — conflict-free on
//                 BOTH write (64 stride-1 rows) and read (16 stride-1 rows).
// Round-6 post-mortem: 11.8M read-side conflicts (swizzle uneven for
// unaligned bases), 8x B-read redundancy, 1 block/CU (no overlap).

#define B_    32
#define CIN   128
#define LEN   4096
#define COUT  256
#define KW    5
#define TROWS 136   // staged rows per 128-l tile: gl in [l0-4, l0+131]

#define WTF_BYTES (KW * 4 * 16 * 512 * 2)   // 327,680

typedef short          s16x8 __attribute__((ext_vector_type(8)));
typedef float          f32x4v __attribute__((ext_vector_type(4)));
typedef unsigned short u16;

// round-half-even(x*20) - 3, clip to [-128,127], as bf16 bit pattern.
// (x*20f vs x/0.05f: <=1ulp flips ~1e-6/elem, each moves output <=0.64 —
// inside the 2.56 absmax threshold; validated passing round 6.)
__device__ __forceinline__ u16 quant_bf16(float xv) {
    float q = rintf(xv * 20.0f) - 3.0f;
    q = fminf(fmaxf(q, -128.0f), 127.0f);
    return (u16)(__float_as_uint(q) >> 16);
}

// W -> fragment-linear: frag = (k*4 + s)*16 + co16; lane holds
// W[co16*16 + (lane&15)][ci = s*32 + (lane>>4)*8 + j], j=0..7, as bf16.
__global__ __launch_bounds__(256) void wprep_kernel(
        const int* __restrict__ w, const int* __restrict__ bias,
        const float* __restrict__ wscale,
        u16* __restrict__ wtf, float* __restrict__ tbl)
{
    int o    = blockIdx.x * 256 + threadIdx.x;   // 0..20479
    int lane = o & 63, frag = o >> 6;
    int k    = frag >> 6;
    int s    = (frag >> 4) & 3;
    int co   = ((frag & 15) << 4) + (lane & 15);
    int ci   = (s << 5) + ((lane >> 4) << 3);
    u16 q[8];
    #pragma unroll
    for (int j = 0; j < 8; ++j) {
        float f = (float)w[co * (CIN * KW) + (ci + j) * KW + k];  // |v|<=127 exact
        q[j] = (u16)(__float_as_uint(f) >> 16);
    }
    s16x8 v = { (short)q[0], (short)q[1], (short)q[2], (short)q[3],
                (short)q[4], (short)q[5], (short)q[6], (short)q[7] };
    *(s16x8*)(wtf + (size_t)frag * 512 + lane * 8) = v;

    if (blockIdx.x == 0) {                        // requant table: sc, off
        int c = threadIdx.x;                      // 0..255
        float sc = __fdiv_rn(__fmul_rn(0.05f, wscale[c]), 0.1f);
        tbl[c]       = sc;
        tbl[256 + c] = fmaf((float)bias[c], sc, -128.0f);
    }
}

// Block: 256 co x 128 l, 512 threads, 8 waves = 4 co-waves x 2 l-waves.
// Wave = 64co x 64l, acc[4][4]. LDS: [136 rows][128 ci] bf16, 34,816 B,
// swizzle: 16B-chunk index ^= (row & 7). 2 blocks/CU co-resident.
__global__ __launch_bounds__(512, 4) void conv_fused(
        const float* __restrict__ x, const u16* __restrict__ wtf,
        const float* __restrict__ tbl, int* __restrict__ out)
{
    __shared__ u16 smem[TROWS * CIN];   // 34,816 B

    int bid   = blockIdx.x;
    int b     = bid >> 5;
    int ltile = bid & 31;
    int l0    = ltile << 7;
    int tid   = threadIdx.x;
    int wid   = tid >> 6, lane = tid & 63;
    int lr    = lane & 15, lh = lane >> 4;
    int cog   = (wid & 3) << 6;          // 4 co-waves x 64
    int wl    = (wid >> 2) << 6;         // 2 l-waves x 64 (local l base)

    const float* xb = x + (size_t)b * CIN * LEN;

    // ---- stage: row r <-> gl = l0 - 4 + r (clamped = replication pad).
    // Lane = row (stride-1 across wave): loads are 64-consecutive-l dwords
    // (coalesced), LDS b128 writes hit all 8 bank-slots uniformly.
    for (int p = wid; p < 48; p += 8) {
        int row = ((p >> 4) << 6) + lane;         // row-block p>>4, chunk p&15
        int c   = p & 15;
        if (row < TROWS) {
            int gl = l0 - 4 + row;
            gl = min(max(gl, 0), LEN - 1);
            const float* src = xb + (size_t)(c << 3) * LEN + gl;
            u16 q[8];
            #pragma unroll
            for (int j = 0; j < 8; ++j)
                q[j] = quant_bf16(src[(size_t)j * LEN]);
            s16x8 v = { (short)q[0], (short)q[1], (short)q[2], (short)q[3],
                        (short)q[4], (short)q[5], (short)q[6], (short)q[7] };
            *(s16x8*)((char*)smem + (row << 8) + ((c ^ (row & 7)) << 4)) = v;
        }
    }
    __syncthreads();

    // ---- K-loop: 5 taps x 4 ci-quarters; per step 4 af (1KB coalesced) +
    // 4 bf (conflict-free b128) -> 16 MFMAs.
    f32x4v acc[4][4] = {};
    #pragma unroll
    for (int k = 0; k < KW; ++k) {
        #pragma unroll
        for (int s = 0; s < 4; ++s) {
            s16x8 af[4];
            #pragma unroll
            for (int ct = 0; ct < 4; ++ct)
                af[ct] = *(const s16x8*)(
                    wtf + (size_t)(((k * 4 + s) << 4) + (cog >> 4) + ct) * 512 + lane * 8);
            s16x8 bf[4];
            int chunk = (s << 2) + lh;
            #pragma unroll
            for (int lt = 0; lt < 4; ++lt) {
                int row = wl + (lt << 4) + lr + k + 2;
                bf[lt] = *(const s16x8*)((const char*)smem +
                           (row << 8) + ((chunk ^ (row & 7)) << 4));
            }
            #pragma unroll
            for (int ct = 0; ct < 4; ++ct)
                #pragma unroll
                for (int lt = 0; lt < 4; ++lt)
                    acc[ct][lt] = __builtin_amdgcn_mfma_f32_16x16x32_bf16(
                        af[ct], bf[lt], acc[ct][lt], 0, 0, 0);
        }
    }

    // ---- requant epilogue via table: rint(fma(acc, sc, off)), int32 stores ----
    size_t outb = (size_t)b * COUT * LEN;
    #pragma unroll
    for (int ct = 0; ct < 4; ++ct) {
        #pragma unroll
        for (int r = 0; r < 4; ++r) {
            int co = cog + ct * 16 + (lh << 2) + r;
            float scv = tbl[co];
            float off = tbl[256 + co];
            #pragma unroll
            for (int lt = 0; lt < 4; ++lt) {
                int l = l0 + wl + (lt << 4) + lr;
                float o = rintf(fmaf(acc[ct][lt][r], scv, off));
                o = fminf(fmaxf(o, -128.0f), 127.0f);
                out[outb + (size_t)co * LEN + l] = (int)o;
            }
        }
    }
}

extern "C" void kernel_launch(void* const* d_in, const int* in_sizes, int n_in,
                              void* d_out, int out_size, void* d_ws, size_t ws_size,
                              hipStream_t stream)
{
    const float* x    = (const float*)d_in[0];
    const int*   w    = (const int*)d_in[1];
    const int*   bias = (const int*)d_in[2];
    const float* wsc  = (const float*)d_in[3];
    int* out = (int*)d_out;

    u16*   wtf = (u16*)d_ws;                        // 327,680 B
    float* tbl = (float*)((char*)d_ws + WTF_BYTES); // +2 KB

    wprep_kernel<<<dim3(80), dim3(256), 0, stream>>>(w, bias, wsc, wtf, tbl);
    conv_fused<<<dim3(B_ * 32), dim3(512), 0, stream>>>(x, wtf, tbl, out);
}

// Round 9
// 69.929 us; speedup vs baseline: 1.4345x; 1.1128x over previous
//
#include <hip/hip_runtime.h>

// QuantizedConv1d on MI355X (gfx950) — round 9
// B=32, CIN=128, L=4096, COUT=256, K=5, replication pad 2.
//   wprep_kernel: W int32 -> fragment-linear bf16 wtf[320][64][8] + requant tbl
//   conv_fused:   256 thr, 4 waves = 2co x 2l, wave = 64co x 64l (acc 4x4).
//                 SWAPPED mfma operands (A=X, B=W) -> D: col=co, row=l ->
//                 dwordx4 epilogue stores (16 insts vs 64) + per-lane sc/off.
//                 Grid 2048, XCD-contiguous remap: co-half pairs share the
//                 same X tile on the same XCD (L2 hit). 4 blocks/CU.
// Round-8 post-mortem: conflicts fixed (2.6M), but only 2 blocks/CU of
// phase overlap and a 64-scalar-store epilogue; nothing saturated.

#define B_    32
#define CIN   128
#define LEN   4096
#define COUT  256
#define KW    5
#define TROWS 136   // staged rows: gl in [l0-4, l0+131]

#define WTF_BYTES (KW * 4 * 16 * 512 * 2)   // 327,680

typedef short          s16x8 __attribute__((ext_vector_type(8)));
typedef float          f32x4v __attribute__((ext_vector_type(4)));
typedef int            i32x4  __attribute__((ext_vector_type(4)));
typedef unsigned short u16;

// round-half-even(x*20) - 3, clip to [-128,127], as bf16 bit pattern.
// (x*20f vs x/0.05f: <=1ulp flips ~1e-6/elem, each moves output <=0.64 —
// inside the 2.56 absmax threshold; validated passing rounds 6/8.)
__device__ __forceinline__ u16 quant_bf16(float xv) {
    float q = rintf(xv * 20.0f) - 3.0f;
    q = fminf(fmaxf(q, -128.0f), 127.0f);
    return (u16)(__float_as_uint(q) >> 16);
}

// W -> fragment-linear: frag = (k*4 + s)*16 + co16; lane holds
// W[co16*16 + (lane&15)][ci = s*32 + (lane>>4)*8 + j], j=0..7, as bf16.
__global__ __launch_bounds__(256) void wprep_kernel(
        const int* __restrict__ w, const int* __restrict__ bias,
        const float* __restrict__ wscale,
        u16* __restrict__ wtf, float* __restrict__ tbl)
{
    int o    = blockIdx.x * 256 + threadIdx.x;   // 0..20479
    int lane = o & 63, frag = o >> 6;
    int k    = frag >> 6;
    int s    = (frag >> 4) & 3;
    int co   = ((frag & 15) << 4) + (lane & 15);
    int ci   = (s << 5) + ((lane >> 4) << 3);
    u16 q[8];
    #pragma unroll
    for (int j = 0; j < 8; ++j) {
        float f = (float)w[co * (CIN * KW) + (ci + j) * KW + k];  // |v|<=127 exact
        q[j] = (u16)(__float_as_uint(f) >> 16);
    }
    s16x8 v = { (short)q[0], (short)q[1], (short)q[2], (short)q[3],
                (short)q[4], (short)q[5], (short)q[6], (short)q[7] };
    *(s16x8*)(wtf + (size_t)frag * 512 + lane * 8) = v;

    if (blockIdx.x == 0) {                        // requant table: sc, off
        int c = threadIdx.x;                      // 0..255
        float sc = __fdiv_rn(__fmul_rn(0.05f, wscale[c]), 0.1f);
        tbl[c]       = sc;
        tbl[256 + c] = fmaf((float)bias[c], sc, -128.0f);
    }
}

// Block: 128 co x 128 l, 256 threads, 4 waves = 2 co-waves x 2 l-waves.
// Wave = 64co x 64l, acc[4][4]. LDS: [136 rows][128 ci] bf16 swizzled
// (chunk ^= row&7), 34,816 B. 4 blocks/CU co-resident (LDS 139KB, 16 waves,
// 128 regs/wave). Grid 2048 = B(32) x ltile(32) x cohalf(2), XCD-chunked.
__global__ __launch_bounds__(256, 4) void conv_fused(
        const float* __restrict__ x, const u16* __restrict__ wtf,
        const float* __restrict__ tbl, int* __restrict__ out)
{
    __shared__ u16 smem[TROWS * CIN];   // 34,816 B

    // XCD-contiguous bijective remap (2048 = 8 XCDs x 256): hardware assigns
    // blockIdx%8 -> XCD, so orig ids [x*256, x*256+256) land on XCD x.
    // Pairs (cohalf 0/1) are consecutive orig -> same XCD, adjacent in time.
    int orig  = (blockIdx.x & 7) * 256 + (blockIdx.x >> 3);
    int ch    = orig & 1;                 // co half (0: co 0..127, 1: 128..255)
    int ltile = (orig >> 1) & 31;
    int b     = orig >> 6;
    int l0    = ltile << 7;
    int tid   = threadIdx.x;
    int wid   = tid >> 6, lane = tid & 63;
    int lr    = lane & 15, lh = lane >> 4;
    int cog   = (ch << 7) + ((wid & 1) << 6);   // wave co base
    int wl    = (wid >> 1) << 6;                // wave local-l base {0,64}

    const float* xb = x + (size_t)b * CIN * LEN;

    // ---- stage: row r <-> gl = l0 - 4 + r (clamped = replication pad).
    // Lane = row (stride-1): coalesced 256B loads; b128 writes conflict-free.
    for (int p = wid; p < 48; p += 4) {
        int row = ((p >> 4) << 6) + lane;        // row-block p>>4, chunk p&15
        int c   = p & 15;
        if (row < TROWS) {
            int gl = l0 - 4 + row;
            gl = min(max(gl, 0), LEN - 1);
            const float* src = xb + (size_t)(c << 3) * LEN + gl;
            u16 q[8];
            #pragma unroll
            for (int j = 0; j < 8; ++j)
                q[j] = quant_bf16(src[(size_t)j * LEN]);
            s16x8 v = { (short)q[0], (short)q[1], (short)q[2], (short)q[3],
                        (short)q[4], (short)q[5], (short)q[6], (short)q[7] };
            *(s16x8*)((char*)smem + (row << 8) + ((c ^ (row & 7)) << 4)) = v;
        }
    }
    __syncthreads();

    // ---- K-loop: 5 taps x 4 ci-quarters; 4 af (1KB coalesced, L2) +
    // 4 bf (conflict-free b128) -> 16 MFMAs. SWAPPED: A=X (row=l), B=W
    // (col=co) so D rows are l (4 consecutive per acc reg).
    f32x4v acc[4][4] = {};
    #pragma unroll
    for (int k = 0; k < KW; ++k) {
        #pragma unroll
        for (int s = 0; s < 4; ++s) {
            s16x8 af[4];
            #pragma unroll
            for (int ct = 0; ct < 4; ++ct)
                af[ct] = *(const s16x8*)(
                    wtf + (size_t)(((k * 4 + s) << 4) + (cog >> 4) + ct) * 512 + lane * 8);
            s16x8 bf[4];
            int chunk = (s << 2) + lh;
            #pragma unroll
            for (int lt = 0; lt < 4; ++lt) {
                int row = wl + (lt << 4) + lr + k + 2;
                bf[lt] = *(const s16x8*)((const char*)smem +
                           (row << 8) + ((chunk ^ (row & 7)) << 4));
            }
            #pragma unroll
            for (int ct = 0; ct < 4; ++ct)
                #pragma unroll
                for (int lt = 0; lt < 4; ++lt)
                    acc[ct][lt] = __builtin_amdgcn_mfma_f32_16x16x32_bf16(
                        bf[lt], af[ct], acc[ct][lt], 0, 0, 0);
        }
    }

    // ---- requant epilogue: col=co=cog+ct*16+lr (per-lane sc/off), row=l.
    // acc[ct][lt] = 4 consecutive l at fixed co -> one dwordx4 store each.
    size_t outb = (size_t)b * COUT * LEN;
    #pragma unroll
    for (int ct = 0; ct < 4; ++ct) {
        int co = cog + (ct << 4) + lr;
        float scv = tbl[co];
        float off = tbl[256 + co];
        int* orow = out + outb + (size_t)co * LEN + l0 + wl + (lh << 2);
        #pragma unroll
        for (int lt = 0; lt < 4; ++lt) {
            i32x4 pk;
            #pragma unroll
            for (int r = 0; r < 4; ++r) {
                float o = rintf(fmaf(acc[ct][lt][r], scv, off));
                o = fminf(fmaxf(o, -128.0f), 127.0f);
                pk[r] = (int)o;
            }
            *(i32x4*)(orow + (lt << 4)) = pk;
        }
    }
}

extern "C" void kernel_launch(void* const* d_in, const int* in_sizes, int n_in,
                              void* d_out, int out_size, void* d_ws, size_t ws_size,
                              hipStream_t stream)
{
    const float* x    = (const float*)d_in[0];
    const int*   w    = (const int*)d_in[1];
    const int*   bias = (const int*)d_in[2];
    const float* wsc  = (const float*)d_in[3];
    int* out = (int*)d_out;

    u16*   wtf = (u16*)d_ws;                        // 327,680 B
    float* tbl = (float*)((char*)d_ws + WTF_BYTES); // +2 KB

    wprep_kernel<<<dim3(80), dim3(256), 0, stream>>>(w, bias, wsc, wtf, tbl);
    conv_fused<<<dim3(2048), dim3(256), 0, stream>>>(x, wtf, tbl, out);
}